// Round 1
// baseline (180.246 us; speedup 1.0000x reference)
//
#include <hip/hip_runtime.h>

// CapsNet conv + dynamic routing, fully fused: one block per (b, ho, wo).
// Block = 1024 threads: thread t -> (tr = t>>5 in 0..31 : i-tile, tc = t&31 : capsule c).
// Thread register tile: votes v[j][n] = votes[i=8*tr+j][c=tc][n], j,n in 0..8.

#define BS 16
#define CI 256
#define CO 32
#define NO 8
#define HI 20
#define WI 20
#define HO 6
#define WO 6
#define NTAP 81          // 9x9
#define XSTRIDE 260      // padded row length for xw[tap][i] (keeps 16B alignment, spreads banks)
#define WCH 27           // W taps per chunk (3 chunks)
#define NTHREADS 1024

__global__ __launch_bounds__(NTHREADS) void caps_fused_kernel(
    const float* __restrict__ x,     // [16,256,1,20,20]
    const float* __restrict__ Wt,    // [256,1,9,9]
    const float* __restrict__ bias,  // [32,8,1,1]
    float* __restrict__ out)         // [16,32,8,6,6]
{
    __shared__ float xw[NTAP * XSTRIDE];   // x windows, [tap][i]   (84240 B)
    __shared__ float wl[WCH * 256];        // W chunk,   [tt][f]    (27648 B)
    __shared__ float red[16 * 288];        // reduction, [wave][tc*9+n] (18432 B)
    __shared__ float actl[CO * NO];        // activation broadcast  (1024 B)

    const int t   = threadIdx.x;
    const int blk = blockIdx.x;
    const int b   = blk / (HO * WO);
    const int hw  = blk % (HO * WO);
    const int h   = hw / WO;
    const int w   = hw % WO;

    const int tr   = t >> 5;   // 0..31
    const int tc   = t & 31;   // 0..31 (= capsule c)
    const int wave = t >> 6;   // 0..15
    const int lane = t & 63;

    // ---- stage x window: xw[kh*9+kw][i] = x[b,i,0,2h+kh,2w+kw]
    for (int p = t; p < CI * 9; p += NTHREADS) {
        int i  = p / 9;
        int kh = p - i * 9;
        const float* src = x + ((b * CI + i) * HI + (2 * h + kh)) * WI + 2 * w;
        #pragma unroll
        for (int kw = 0; kw < 9; ++kw)
            xw[(kh * 9 + kw) * XSTRIDE + i] = src[kw];
    }

    // ---- conv accumulators (votes)
    float v[8][8];
    #pragma unroll
    for (int j = 0; j < 8; ++j)
        #pragma unroll
        for (int n = 0; n < 8; ++n) v[j][n] = 0.f;

    // ---- conv: GEMM M=256(i) x N=256(f) x K=81, W staged in 3 chunks of 27 taps
    for (int ch = 0; ch < 3; ++ch) {
        __syncthreads();   // x ready (ch==0) / previous chunk compute done
        for (int p = t; p < WCH * 256; p += NTHREADS) {
            int tt = p >> 8;
            int f  = p & 255;
            wl[tt * 256 + f] = Wt[f * NTAP + ch * WCH + tt];
        }
        __syncthreads();
        #pragma unroll
        for (int tt = 0; tt < WCH; ++tt) {
            const int tap = ch * WCH + tt;
            float4 xa = *(const float4*)&xw[tap * XSTRIDE + 8 * tr];
            float4 xb = *(const float4*)&xw[tap * XSTRIDE + 8 * tr + 4];
            float4 wa = *(const float4*)&wl[tt * 256 + 8 * tc];
            float4 wb = *(const float4*)&wl[tt * 256 + 8 * tc + 4];
            float xs[8] = {xa.x, xa.y, xa.z, xa.w, xb.x, xb.y, xb.z, xb.w};
            float ws[8] = {wa.x, wa.y, wa.z, wa.w, wb.x, wb.y, wb.z, wb.w};
            #pragma unroll
            for (int j = 0; j < 8; ++j)
                #pragma unroll
                for (int n = 0; n < 8; ++n)
                    v[j][n] = fmaf(xs[j], ws[n], v[j][n]);
        }
    }

    // ---- dynamic routing (3 iterations), logits in registers
    float lg[8];
    #pragma unroll
    for (int j = 0; j < 8; ++j) lg[j] = 0.f;

    float bias_r = 0.f;
    if (t < CO * NO) bias_r = bias[t];   // t = c*8+n

    for (int it = 0; it < 3; ++it) {
        // route = softmax over c (c spread across the 32-lane half of the wave)
        float r[8];
        if (it == 0) {
            #pragma unroll
            for (int j = 0; j < 8; ++j) r[j] = 1.0f / 32.0f;   // softmax(0)
        } else {
            float s[8];
            #pragma unroll
            for (int j = 0; j < 8; ++j) { r[j] = __expf(lg[j]); s[j] = r[j]; }
            #pragma unroll
            for (int m = 1; m <= 16; m <<= 1) {
                #pragma unroll
                for (int j = 0; j < 8; ++j) s[j] += __shfl_xor(s[j], m, 64);
            }
            #pragma unroll
            for (int j = 0; j < 8; ++j) r[j] = r[j] / s[j];
        }

        // preactivate partial over this thread's 8 i's: pp[n] = sum_j r[j]*v[j][n]
        float pp[8];
        #pragma unroll
        for (int n = 0; n < 8; ++n) {
            float a = 0.f;
            #pragma unroll
            for (int j = 0; j < 8; ++j) a = fmaf(r[j], v[j][n], a);
            pp[n] = a;
        }
        // reduce over i: pair of tr within wave (xor 32), then 16 waves via LDS
        #pragma unroll
        for (int n = 0; n < 8; ++n) pp[n] += __shfl_xor(pp[n], 32, 64);
        if (lane < 32) {
            #pragma unroll
            for (int n = 0; n < 8; ++n) red[wave * 288 + tc * 9 + n] = pp[n];
        }
        __syncthreads();

        if (t < CO * NO) {
            const int c = t >> 3, n = t & 7;
            float s = 0.f;
            #pragma unroll
            for (int wv = 0; wv < 16; ++wv) s += red[wv * 288 + c * 9 + n];
            s += bias_r;                       // preactivate[c][n]
            // squash over n (8 lanes per c)
            float sq = s * s;
            #pragma unroll
            for (int m = 1; m <= 4; m <<= 1) sq += __shfl_xor(sq, m, 64);
            const float nrm = sqrtf(sq);
            const float a = s * nrm / (1.f + sq);
            if (it == 2)
                out[(((b * CO + c) * NO + n) * HO + h) * WO + w] = a;
            else
                actl[t] = a;
        }
        __syncthreads();

        if (it < 2) {
            // distances: lg[j] += sum_n v[j][n] * act[c=tc][n]
            float av[8];
            #pragma unroll
            for (int n = 0; n < 8; ++n) av[n] = actl[tc * 8 + n];
            #pragma unroll
            for (int j = 0; j < 8; ++j) {
                float d = 0.f;
                #pragma unroll
                for (int n = 0; n < 8; ++n) d = fmaf(v[j][n], av[n], d);
                lg[j] += d;
            }
        }
    }
}

extern "C" void kernel_launch(void* const* d_in, const int* in_sizes, int n_in,
                              void* d_out, int out_size, void* d_ws, size_t ws_size,
                              hipStream_t stream) {
    const float* x    = (const float*)d_in[0];
    const float* Wt   = (const float*)d_in[1];
    const float* bias = (const float*)d_in[2];
    float* out = (float*)d_out;
    dim3 grid(BS * HO * WO);   // 576 blocks, one per (b,h,w)
    dim3 block(NTHREADS);
    caps_fused_kernel<<<grid, block, 0, stream>>>(x, Wt, bias, out);
}

// Round 2
// 69.161 us; speedup vs baseline: 2.6062x; 2.6062x over previous
//
#include <hip/hip_runtime.h>

// CapsNet conv + dynamic routing, fused, bf16 MFMA conv.
// One block per (b, ho, wo); 1024 threads = 16 waves in a 4(f) x 4(i) grid.
// Conv computes votes^T: D[f][i] via mfma_f32_16x16x32_bf16 with A=W (M=f, K=taps),
// B=x-window^T (K=taps, N=i). Votes live in the 64-VGPR accumulator for all
// 3 routing iterations.
//
// Lane decomposition (l = lane, q = l>>4, il = l&15), wave (wf, wi):
//   acc[tf][ti].r = votes[ i = 64*wi+16*ti+il ][ f = 64*wf+16*tf+4*q+r ]
//   c = f>>3 = 8*wf + 2*tf + (q>>1)      (capsule)
//   n = f&7  = 4*(q&1) + r               (pose component, 4 in-register!)

#define BS 16
#define CI 256
#define CO 32
#define NO 8
#define HI 20
#define WI 20
#define HO 6
#define WO 6
#define NTAP 81
#define KPAD 104        // K pitch in bf16 elems: 81 real, 96 consumed by MFMA, 104 for banks
#define NTHREADS 1024

typedef __attribute__((ext_vector_type(8))) short bf16x8;
typedef __attribute__((ext_vector_type(4))) float f32x4;

__device__ __forceinline__ ushort f2bf(float x) {
    union { float f; unsigned u; } v; v.f = x;
    unsigned r = v.u + 0x7FFFu + ((v.u >> 16) & 1u);   // round-to-nearest-even
    return (ushort)(r >> 16);
}

__global__ __launch_bounds__(NTHREADS) void caps_mfma_kernel(
    const float* __restrict__ x,     // [16,256,1,20,20]
    const float* __restrict__ Wt,    // [256,1,9,9]
    const float* __restrict__ bias,  // [32,8,1,1]
    float* __restrict__ out)         // [16,32,8,6,6]
{
    __shared__ __align__(16) ushort xw[CI * KPAD];        // [i][k] bf16  53248 B
    __shared__ __align__(16) ushort wl[CO * NO * KPAD];   // [f][k] bf16  53248 B
    __shared__ __align__(16) float  smx[4 * 256];         // [wf][i] softmax sums
    __shared__ __align__(16) float  pre[4 * 256];         // [wi][c*8+n] preact partials
    __shared__ __align__(16) float  act[256];             // activation broadcast

    const int t   = threadIdx.x;
    const int blk = blockIdx.x;
    const int b   = blk / (HO * WO);
    const int hw  = blk % (HO * WO);
    const int h   = hw / WO;
    const int w   = hw % WO;

    // ---- stage x window (bf16): xw[i][kh*9+kw] = x[b,i,0,2h+kh,2w+kw]
    for (int p = t; p < CI * 9; p += NTHREADS) {
        int i = p / 9, kh = p - i * 9;
        const float* src = x + ((b * CI + i) * HI + (2 * h + kh)) * WI + 2 * w;
        #pragma unroll
        for (int kw = 0; kw < 9; ++kw)
            xw[i * KPAD + kh * 9 + kw] = f2bf(src[kw]);
    }
    // ---- stage W (bf16): wl[f][k] = Wt[f*81+k]  (coalesced over p)
    for (int p = t; p < CO * NO * NTAP; p += NTHREADS) {
        int f = p / NTAP, k = p - f * NTAP;
        wl[f * KPAD + k] = f2bf(Wt[p]);
    }
    // ---- zero-pad k in [81, 104) for both arrays (256 rows each)
    for (int p = t; p < 256 * (KPAD - NTAP); p += NTHREADS) {
        int i = p / (KPAD - NTAP), k = NTAP + (p - i * (KPAD - NTAP));
        xw[i * KPAD + k] = 0;
        wl[i * KPAD + k] = 0;
    }

    const int wid = t >> 6, l = t & 63;
    const int q = l >> 4, il = l & 15;
    const int wf = wid >> 2, wi = wid & 3;

    const float bias_r = (t < 256) ? bias[t] : 0.f;

    __syncthreads();

    // ---- conv via MFMA: 3 K-steps x 16 tiles
    f32x4 acc[4][4];
    #pragma unroll
    for (int tf = 0; tf < 4; ++tf)
        #pragma unroll
        for (int ti = 0; ti < 4; ++ti)
            acc[tf][ti] = (f32x4){0.f, 0.f, 0.f, 0.f};

    #pragma unroll
    for (int ks = 0; ks < 3; ++ks) {
        const int ko = ks * 32 + q * 8;
        bf16x8 af[4], bv[4];
        #pragma unroll
        for (int tf = 0; tf < 4; ++tf)
            af[tf] = *(const bf16x8*)&wl[(wf * 64 + tf * 16 + il) * KPAD + ko];
        #pragma unroll
        for (int ti = 0; ti < 4; ++ti)
            bv[ti] = *(const bf16x8*)&xw[(wi * 64 + ti * 16 + il) * KPAD + ko];
        #pragma unroll
        for (int tf = 0; tf < 4; ++tf)
            #pragma unroll
            for (int ti = 0; ti < 4; ++ti)
                acc[tf][ti] = __builtin_amdgcn_mfma_f32_16x16x32_bf16(
                    af[tf], bv[ti], acc[tf][ti], 0, 0, 0);
    }

    // ---- dynamic routing, 3 iterations
    float lg[4][4];   // logits[i(ti)][c(tf)] — replicated across the n-half lanes
    #pragma unroll
    for (int tf = 0; tf < 4; ++tf)
        #pragma unroll
        for (int ti = 0; ti < 4; ++ti) lg[tf][ti] = 0.f;

    #pragma unroll
    for (int it = 0; it < 3; ++it) {
        // --- route = softmax over c (32 capsules)
        float route[4][4];
        if (it == 0) {
            #pragma unroll
            for (int tf = 0; tf < 4; ++tf)
                #pragma unroll
                for (int ti = 0; ti < 4; ++ti) route[tf][ti] = 0.03125f;
        } else {
            float e[4][4], srow[4] = {0.f, 0.f, 0.f, 0.f};
            #pragma unroll
            for (int tf = 0; tf < 4; ++tf)
                #pragma unroll
                for (int ti = 0; ti < 4; ++ti) {
                    e[tf][ti] = __expf(lg[tf][ti]);
                    srow[ti] += e[tf][ti];
                }
            #pragma unroll
            for (int ti = 0; ti < 4; ++ti)
                srow[ti] += __shfl_xor(srow[ti], 32, 64);   // other c-bit (q>>1)
            if (q == 0) {
                #pragma unroll
                for (int ti = 0; ti < 4; ++ti)
                    smx[wf * 256 + wi * 64 + ti * 16 + il] = srow[ti];
            }
            __syncthreads();
            float rtot[4];
            #pragma unroll
            for (int ti = 0; ti < 4; ++ti) {
                int i = wi * 64 + ti * 16 + il;
                rtot[ti] = 1.0f / (smx[i] + smx[256 + i] + smx[512 + i] + smx[768 + i]);
            }
            #pragma unroll
            for (int tf = 0; tf < 4; ++tf)
                #pragma unroll
                for (int ti = 0; ti < 4; ++ti) route[tf][ti] = e[tf][ti] * rtot[ti];
        }

        // --- preact partial: pp[tf][r] = sum_ti route * votes  (i within lane)
        float pp[4][4];
        #pragma unroll
        for (int tf = 0; tf < 4; ++tf)
            #pragma unroll
            for (int r = 0; r < 4; ++r)
                pp[tf][r] = route[tf][0] * acc[tf][0][r] + route[tf][1] * acc[tf][1][r]
                          + route[tf][2] * acc[tf][2][r] + route[tf][3] * acc[tf][3][r];
        // reduce over il (16 lanes of i)
        #pragma unroll
        for (int m = 1; m <= 8; m <<= 1)
            #pragma unroll
            for (int tf = 0; tf < 4; ++tf)
                #pragma unroll
                for (int r = 0; r < 4; ++r)
                    pp[tf][r] += __shfl_xor(pp[tf][r], m, 64);
        if (il == 0) {
            #pragma unroll
            for (int tf = 0; tf < 4; ++tf) {
                int c = wf * 8 + tf * 2 + (q >> 1);
                f32x4 vv = {pp[tf][0], pp[tf][1], pp[tf][2], pp[tf][3]};
                *(f32x4*)&pre[wi * 256 + c * 8 + (q & 1) * 4] = vv;
            }
        }
        __syncthreads();

        // --- finish preact over wi-waves, + bias, squash over n (threads 0..255)
        if (t < 256) {
            float s = bias_r + pre[t] + pre[256 + t] + pre[512 + t] + pre[768 + t];
            float sq = s * s;
            sq += __shfl_xor(sq, 1, 64);
            sq += __shfl_xor(sq, 2, 64);
            sq += __shfl_xor(sq, 4, 64);
            float a = s * sqrtf(sq) / (1.f + sq);
            if (it == 2) {
                int c = t >> 3, n = t & 7;
                out[(((b * CO + c) * NO + n) * HO + h) * WO + w] = a;
            } else {
                act[t] = a;
            }
        }
        __syncthreads();

        // --- distances -> logits (skip on last iter)
        if (it < 2) {
            #pragma unroll
            for (int tf = 0; tf < 4; ++tf) {
                int c = wf * 8 + tf * 2 + (q >> 1);
                f32x4 av = *(const f32x4*)&act[c * 8 + (q & 1) * 4];
                #pragma unroll
                for (int ti = 0; ti < 4; ++ti) {
                    float d = acc[tf][ti][0] * av[0] + acc[tf][ti][1] * av[1]
                            + acc[tf][ti][2] * av[2] + acc[tf][ti][3] * av[3];
                    d += __shfl_xor(d, 16, 64);   // sum over the other n-half
                    lg[tf][ti] += d;
                }
            }
        }
    }
}

extern "C" void kernel_launch(void* const* d_in, const int* in_sizes, int n_in,
                              void* d_out, int out_size, void* d_ws, size_t ws_size,
                              hipStream_t stream) {
    const float* x    = (const float*)d_in[0];
    const float* Wt   = (const float*)d_in[1];
    const float* bias = (const float*)d_in[2];
    float* out = (float*)d_out;
    dim3 grid(BS * HO * WO);   // 576 blocks, one per (b,h,w)
    dim3 block(NTHREADS);
    caps_mfma_kernel<<<grid, block, 0, stream>>>(x, Wt, bias, out);
}